// Round 1
// baseline (122.238 us; speedup 1.0000x reference)
//
#include <hip/hip_runtime.h>

#define BTOT 128     // B*T
#define NN   512
#define FIN  128
#define FOUT 64
#define NEG_INF -9000000000000000.0f

#define F4E(v,i) (((float*)&(v))[i])

// ---------- A0: transpose W[64][128] -> Wt[128][64] ----------
__global__ void k_transpose_w(const float* __restrict__ W, float* __restrict__ Wt) {
    int idx = blockIdx.x * 256 + threadIdx.x;       // 8192 total
    int k = idx >> 6, o = idx & 63;
    Wt[idx] = W[o * FIN + k];
}

// ---------- A: h = x @ W^T, src = h.a1, dst = h.a2 ----------
// grid (8, 128), 256 threads. Each block: 64 n-rows x 64 o-cols, K=128 in 2 tiles.
__global__ void k_feat(const float* __restrict__ x, const float* __restrict__ Wt,
                       const float* __restrict__ a,
                       float* __restrict__ h, float* __restrict__ srcv,
                       float* __restrict__ dstv) {
    __shared__ float Xs[64 * 68];    // x tile, padded stride 68
    __shared__ float Wts[64 * 64];   // Wt tile [k][o]
    const int t  = threadIdx.x;
    const int bt = blockIdx.y;
    const int n0 = blockIdx.x * 64;
    const int tx = t & 15, ty = t >> 4;

    float acc[4][4] = {};
    const float* xbase = x + (bt * NN + n0) * FIN;

    for (int kt = 0; kt < 2; ++kt) {
        __syncthreads();
#pragma unroll
        for (int r = 0; r < 4; ++r) {
            int lin = r * 1024 + 4 * t;
            int row = lin >> 6, col = lin & 63;
            *(float4*)&Xs[row * 68 + col] =
                *(const float4*)&xbase[row * FIN + kt * 64 + col];
        }
        {
            const float* wb = Wt + kt * 64 * FOUT;   // contiguous 4096 floats
#pragma unroll
            for (int r = 0; r < 4; ++r) {
                int lin = r * 1024 + 4 * t;
                *(float4*)&Wts[lin] = *(const float4*)&wb[lin];
            }
        }
        __syncthreads();
#pragma unroll
        for (int k4 = 0; k4 < 16; ++k4) {
            float4 af[4], bf[4];
#pragma unroll
            for (int ii = 0; ii < 4; ++ii)
                af[ii] = *(float4*)&Xs[(4 * ty + ii) * 68 + 4 * k4];
#pragma unroll
            for (int kk = 0; kk < 4; ++kk)
                bf[kk] = *(float4*)&Wts[(4 * k4 + kk) * 64 + 4 * tx];
#pragma unroll
            for (int ii = 0; ii < 4; ++ii)
#pragma unroll
                for (int kk = 0; kk < 4; ++kk) {
                    float av = F4E(af[ii], kk);
#pragma unroll
                    for (int oo = 0; oo < 4; ++oo)
                        acc[ii][oo] = fmaf(av, F4E(bf[kk], oo), acc[ii][oo]);
                }
        }
    }

    // write h
    float* hb = h + (bt * NN + n0) * FOUT;
#pragma unroll
    for (int ii = 0; ii < 4; ++ii) {
        float4 v = make_float4(acc[ii][0], acc[ii][1], acc[ii][2], acc[ii][3]);
        *(float4*)&hb[(4 * ty + ii) * FOUT + 4 * tx] = v;
    }

    // src/dst: per-row dot with a1/a2, reduce across the 16 tx lanes
    float4 a1v = *(const float4*)&a[4 * tx];
    float4 a2v = *(const float4*)&a[FOUT + 4 * tx];
#pragma unroll
    for (int ii = 0; ii < 4; ++ii) {
        float s1 = acc[ii][0] * a1v.x + acc[ii][1] * a1v.y +
                   acc[ii][2] * a1v.z + acc[ii][3] * a1v.w;
        float s2 = acc[ii][0] * a2v.x + acc[ii][1] * a2v.y +
                   acc[ii][2] * a2v.z + acc[ii][3] * a2v.w;
#pragma unroll
        for (int off = 8; off; off >>= 1) {
            s1 += __shfl_down(s1, off, 16);
            s2 += __shfl_down(s2, off, 16);
        }
        if (tx == 0) {
            srcv[bt * NN + n0 + 4 * ty + ii] = s1;
            dstv[bt * NN + n0 + 4 * ty + ii] = s2;
        }
    }
}

// ---------- B: fused att (exp, no-max softmax) + PV GEMM ----------
// grid (8, 128), 256 threads. Block: 64 i-rows, loop 8 j-tiles of 64.
__global__ void k_attn(const float* __restrict__ h, const float* __restrict__ srcv,
                       const float* __restrict__ dstv, const int* __restrict__ adj,
                       const float* __restrict__ adj_we, float* __restrict__ out) {
    __shared__ float ps[64 * 68];    // p tile, padded
    __shared__ float hs[64 * 64];    // h tile [j][o]
    __shared__ float dst_s[512];
    __shared__ float src_s[64];
    __shared__ float den_s[64];
    const int t  = threadIdx.x;
    const int bt = blockIdx.y;
    const int i0 = blockIdx.x * 64;
    const int tx = t & 15, ty = t >> 4;

    if (t < 64) { src_s[t] = srcv[bt * NN + i0 + t]; den_s[t] = 0.f; }
    for (int r = t; r < 512; r += 256) dst_s[r] = dstv[bt * NN + r];

    float acc[4][4] = {};
    const float* hb = h + bt * NN * FOUT;

    for (int jt = 0; jt < 8; ++jt) {
        const int j0 = jt * 64;
        __syncthreads();   // prev tile's reads done; phase-0 writes visible (jt==0)

        // load h tile (contiguous 4096 floats)
#pragma unroll
        for (int r = 0; r < 4; ++r) {
            int lin = r * 1024 + 4 * t;
            *(float4*)&hs[lin] = *(const float4*)&hb[j0 * FOUT + lin];
        }

        // compute p tile
        {
            const int jj = t & 63;
            const int ibase = (t >> 6) * 16;
            const float dj = dst_s[j0 + jj];
#pragma unroll
            for (int ii = 0; ii < 16; ++ii) {
                int i = ibase + ii;
                int gi = (i0 + i) * NN + j0 + jj;
                int av  = adj[gi];
                float w = adj_we[gi];
                float s = src_s[i] + dj;
                float e = s > 0.f ? s : 0.01f * s;
                float att = (av > 0 ? e : NEG_INF) * w;   // matches ref incl. w==0
                ps[i * 68 + jj] = __expf(att);            // masked -> exp(-huge)=0
            }
        }
        __syncthreads();

        // denominator partial: wave w owns rows 16w..16w+15
        {
            const int wv = t >> 6, lane = t & 63;
#pragma unroll
            for (int r = 0; r < 16; ++r) {
                int i = wv * 16 + r;
                float v = ps[i * 68 + lane];
#pragma unroll
                for (int off = 32; off; off >>= 1) v += __shfl_down(v, off);
                if (lane == 0) den_s[i] += v;
            }
        }

        // PV GEMM: acc[i][o] += p[i][k] * h[k][o], K=64
#pragma unroll
        for (int k4 = 0; k4 < 16; ++k4) {
            float4 af[4], bf[4];
#pragma unroll
            for (int ii = 0; ii < 4; ++ii)
                af[ii] = *(float4*)&ps[(4 * ty + ii) * 68 + 4 * k4];
#pragma unroll
            for (int kk = 0; kk < 4; ++kk)
                bf[kk] = *(float4*)&hs[(4 * k4 + kk) * 64 + 4 * tx];
#pragma unroll
            for (int ii = 0; ii < 4; ++ii)
#pragma unroll
                for (int kk = 0; kk < 4; ++kk) {
                    float av = F4E(af[ii], kk);
#pragma unroll
                    for (int oo = 0; oo < 4; ++oo)
                        acc[ii][oo] = fmaf(av, F4E(bf[kk], oo), acc[ii][oo]);
                }
        }
    }
    __syncthreads();

    float* ob = out + (bt * NN + i0) * FOUT;
#pragma unroll
    for (int ii = 0; ii < 4; ++ii) {
        float inv = 1.0f / den_s[4 * ty + ii];
        float4 v = make_float4(acc[ii][0] * inv, acc[ii][1] * inv,
                               acc[ii][2] * inv, acc[ii][3] * inv);
        *(float4*)&ob[(4 * ty + ii) * FOUT + 4 * tx] = v;
    }
}

extern "C" void kernel_launch(void* const* d_in, const int* in_sizes, int n_in,
                              void* d_out, int out_size, void* d_ws, size_t ws_size,
                              hipStream_t stream) {
    const float* x      = (const float*)d_in[0];
    const float* W      = (const float*)d_in[1];
    const float* a      = (const float*)d_in[2];
    const int*   adj    = (const int*)d_in[3];
    const float* adj_we = (const float*)d_in[4];
    float* out = (float*)d_out;
    float* ws  = (float*)d_ws;

    float* Wt   = ws;                 // 8192
    float* h    = Wt + 8192;          // 128*512*64 = 4194304
    float* srcv = h + BTOT * NN * FOUT;  // 65536
    float* dstv = srcv + BTOT * NN;      // 65536

    hipLaunchKernelGGL(k_transpose_w, dim3(32), dim3(256), 0, stream, W, Wt);
    hipLaunchKernelGGL(k_feat, dim3(8, 128), dim3(256), 0, stream,
                       x, Wt, a, h, srcv, dstv);
    hipLaunchKernelGGL(k_attn, dim3(8, 128), dim3(256), 0, stream,
                       h, srcv, dstv, adj, adj_we, out);
}

// Round 2
// 71.115 us; speedup vs baseline: 1.7189x; 1.7189x over previous
//
#include <hip/hip_runtime.h>
#include <hip/hip_bf16.h>

#define BTOT 128     // B*T
#define NN   512
#define FIN  128
#define FOUT 64
#define NEG_INF -9000000000000000.0f

typedef __attribute__((ext_vector_type(8))) short bf16x8;
typedef __attribute__((ext_vector_type(4))) float f32x4;

#define F4E(v,i) (((float*)&(v))[i])

static __device__ inline ushort f2bf(float f) {
    __hip_bfloat16 h = __float2bfloat16(f);
    return *(ushort*)&h;
}

// ---------- A0: transpose W[64][128] -> Wt[128][64] ----------
__global__ void k_transpose_w(const float* __restrict__ W, float* __restrict__ Wt) {
    int idx = blockIdx.x * 256 + threadIdx.x;       // 8192 total
    int k = idx >> 6, o = idx & 63;
    Wt[idx] = W[o * FIN + k];
}

// ---------- A: h = x @ W^T (fp32), emit ht bf16 [bt][o][j], src, dst ----------
__global__ void k_feat(const float* __restrict__ x, const float* __restrict__ Wt,
                       const float* __restrict__ a,
                       ushort* __restrict__ ht, float* __restrict__ srcv,
                       float* __restrict__ dstv) {
    __shared__ float Xs[64 * 68];    // x tile, padded stride 68
    __shared__ float Wts[64 * 64];   // Wt tile [k][o]
    __shared__ ushort Tt[64 * 72];   // transpose staging [o][n] bf16, stride 72
    const int t  = threadIdx.x;
    const int bt = blockIdx.y;
    const int n0 = blockIdx.x * 64;
    const int tx = t & 15, ty = t >> 4;

    float acc[4][4] = {};
    const float* xbase = x + (bt * NN + n0) * FIN;

    for (int kt = 0; kt < 2; ++kt) {
        __syncthreads();
#pragma unroll
        for (int r = 0; r < 4; ++r) {
            int lin = r * 1024 + 4 * t;
            int row = lin >> 6, col = lin & 63;
            *(float4*)&Xs[row * 68 + col] =
                *(const float4*)&xbase[row * FIN + kt * 64 + col];
        }
        {
            const float* wb = Wt + kt * 64 * FOUT;   // contiguous 4096 floats
#pragma unroll
            for (int r = 0; r < 4; ++r) {
                int lin = r * 1024 + 4 * t;
                *(float4*)&Wts[lin] = *(const float4*)&wb[lin];
            }
        }
        __syncthreads();
#pragma unroll
        for (int k4 = 0; k4 < 16; ++k4) {
            float4 af[4], bf[4];
#pragma unroll
            for (int ii = 0; ii < 4; ++ii)
                af[ii] = *(float4*)&Xs[(4 * ty + ii) * 68 + 4 * k4];
#pragma unroll
            for (int kk = 0; kk < 4; ++kk)
                bf[kk] = *(float4*)&Wts[(4 * k4 + kk) * 64 + 4 * tx];
#pragma unroll
            for (int ii = 0; ii < 4; ++ii)
#pragma unroll
                for (int kk = 0; kk < 4; ++kk) {
                    float av = F4E(af[ii], kk);
#pragma unroll
                    for (int oo = 0; oo < 4; ++oo)
                        acc[ii][oo] = fmaf(av, F4E(bf[kk], oo), acc[ii][oo]);
                }
        }
    }

    // src/dst: per-row dot with a1/a2, reduce across the 16 tx lanes
    float4 a1v = *(const float4*)&a[4 * tx];
    float4 a2v = *(const float4*)&a[FOUT + 4 * tx];
#pragma unroll
    for (int ii = 0; ii < 4; ++ii) {
        float s1 = acc[ii][0] * a1v.x + acc[ii][1] * a1v.y +
                   acc[ii][2] * a1v.z + acc[ii][3] * a1v.w;
        float s2 = acc[ii][0] * a2v.x + acc[ii][1] * a2v.y +
                   acc[ii][2] * a2v.z + acc[ii][3] * a2v.w;
#pragma unroll
        for (int off = 8; off; off >>= 1) {
            s1 += __shfl_down(s1, off, 16);
            s2 += __shfl_down(s2, off, 16);
        }
        if (tx == 0) {
            srcv[bt * NN + n0 + 4 * ty + ii] = s1;
            dstv[bt * NN + n0 + 4 * ty + ii] = s2;
        }
    }

    // transpose acc -> Tt[o][n] bf16 (pack 2 consecutive n into one dword)
#pragma unroll
    for (int oo = 0; oo < 4; ++oo)
#pragma unroll
        for (int ip = 0; ip < 2; ++ip) {
            uint v = (uint)f2bf(acc[2 * ip][oo]) |
                     ((uint)f2bf(acc[2 * ip + 1][oo]) << 16);
            *(uint*)&Tt[(4 * tx + oo) * 72 + 4 * ty + 2 * ip] = v;
        }
    __syncthreads();

    // coalesced write: ht[bt][o][n0 + ...]
#pragma unroll
    for (int q = 0; q < 2; ++q) {
        int idx = 2 * t + q;            // 0..511
        int row = idx >> 3, c8 = idx & 7;
        float4 v = *(float4*)&Tt[row * 72 + c8 * 8];
        *(float4*)&ht[bt * (FOUT * NN) + row * NN + n0 + c8 * 8] = v;
    }
}

// ---------- B: fused att (exp, no-max softmax) + bf16 MFMA PV ----------
// grid (8, 128), 256 threads = 4 waves. Block: 64 i-rows x 64 o-cols, 8 j-tiles.
__global__ void k_attn(const ushort* __restrict__ ht, const float* __restrict__ srcv,
                       const float* __restrict__ dstv, const int* __restrict__ adj,
                       const float* __restrict__ adj_we, float* __restrict__ out) {
    __shared__ ushort ps[64 * 72];   // p tile bf16 [i][k], stride 72
    __shared__ ushort hs[64 * 72];   // h^T tile bf16 [o][k], stride 72
    __shared__ float dst_s[NN];
    __shared__ float src_s[64];

    const int t    = threadIdx.x;
    const int bt   = blockIdx.y;
    const int i0   = blockIdx.x * 64;
    const int lane = t & 63;
    const int wv   = t >> 6;

    if (t < 64) src_s[t] = srcv[bt * NN + i0 + t];
    for (int r = t; r < NN; r += 256) dst_s[r] = dstv[bt * NN + r];

    const int pi = t >> 2;           // p-compute: row
    const int pj = (t & 3) * 16;     // p-compute: col base (16 consecutive j)
    const int* adjr  = adj + (i0 + pi) * NN;
    const float* wr  = adj_we + (i0 + pi) * NN;
    const ushort* htb = ht + bt * (FOUT * NN);

    f32x4 acc0 = {0,0,0,0}, acc1 = {0,0,0,0}, acc2 = {0,0,0,0},
          acc3 = {0,0,0,0}, accd = {0,0,0,0};

    bf16x8 ones;
#pragma unroll
    for (int j = 0; j < 8; ++j) ones[j] = (short)0x3F80;   // bf16 1.0

    __syncthreads();
    const float si = src_s[pi];

    const int arow = (wv * 16 + (lane & 15)) * 72;   // A-frag row base
    const int koff = (lane >> 4) * 8;                // k-chunk within frag

    for (int jt = 0; jt < 8; ++jt) {
        const int j0 = jt * 64;

        // stage hs (bf16, contiguous 16B per lane)
#pragma unroll
        for (int q = 0; q < 2; ++q) {
            int idx = 2 * t + q;             // 0..511
            int row = idx >> 3, c8 = idx & 7;
            float4 v = *(const float4*)&htb[row * NN + j0 + c8 * 8];
            *(float4*)&hs[row * 72 + c8 * 8] = v;
        }

        // compute p (16 elems per thread, contiguous j), pack bf16
        ushort pu[16];
#pragma unroll
        for (int q = 0; q < 4; ++q) {
            int4   av4 = *(const int4*)&adjr[j0 + pj + 4 * q];
            float4 wv4 = *(const float4*)&wr[j0 + pj + 4 * q];
            float4 dv4 = *(const float4*)&dst_s[j0 + pj + 4 * q];
#pragma unroll
            for (int e = 0; e < 4; ++e) {
                int   ad = ((const int*)&av4)[e];
                float w  = ((const float*)&wv4)[e];
                float s  = si + ((const float*)&dv4)[e];
                float lr = s > 0.f ? s : 0.01f * s;
                float att = (ad > 0 ? lr : NEG_INF) * w;   // matches ref incl. w==0
                pu[4 * q + e] = f2bf(__expf(att));          // masked -> 0
            }
        }
        *(float4*)&ps[pi * 72 + pj]     = *(float4*)&pu[0];
        *(float4*)&ps[pi * 72 + pj + 8] = *(float4*)&pu[8];
        __syncthreads();

        // MFMA: wave wv owns rows 16wv..16wv+15, all 64 o-cols + den
#pragma unroll
        for (int s = 0; s < 2; ++s) {
            bf16x8 afr = *(bf16x8*)&ps[arow + s * 32 + koff];
            bf16x8 b0  = *(bf16x8*)&hs[( 0 + (lane & 15)) * 72 + s * 32 + koff];
            bf16x8 b1  = *(bf16x8*)&hs[(16 + (lane & 15)) * 72 + s * 32 + koff];
            bf16x8 b2  = *(bf16x8*)&hs[(32 + (lane & 15)) * 72 + s * 32 + koff];
            bf16x8 b3  = *(bf16x8*)&hs[(48 + (lane & 15)) * 72 + s * 32 + koff];
            acc0 = __builtin_amdgcn_mfma_f32_16x16x32_bf16(afr, b0, acc0, 0, 0, 0);
            acc1 = __builtin_amdgcn_mfma_f32_16x16x32_bf16(afr, b1, acc1, 0, 0, 0);
            acc2 = __builtin_amdgcn_mfma_f32_16x16x32_bf16(afr, b2, acc2, 0, 0, 0);
            acc3 = __builtin_amdgcn_mfma_f32_16x16x32_bf16(afr, b3, acc3, 0, 0, 0);
            accd = __builtin_amdgcn_mfma_f32_16x16x32_bf16(afr, ones, accd, 0, 0, 0);
        }
        __syncthreads();
    }

    // epilogue: C/D layout col=lane&15, row=(lane>>4)*4+reg; den in accd same slots
    const int orow = wv * 16 + (lane >> 4) * 4;
    const int ocol = lane & 15;
    float* ob = out + ((long)bt * NN + i0) * FOUT;
#pragma unroll
    for (int reg = 0; reg < 4; ++reg) {
        float inv = 1.0f / accd[reg];
        ob[(orow + reg) * FOUT +  0 + ocol] = acc0[reg] * inv;
        ob[(orow + reg) * FOUT + 16 + ocol] = acc1[reg] * inv;
        ob[(orow + reg) * FOUT + 32 + ocol] = acc2[reg] * inv;
        ob[(orow + reg) * FOUT + 48 + ocol] = acc3[reg] * inv;
    }
}

extern "C" void kernel_launch(void* const* d_in, const int* in_sizes, int n_in,
                              void* d_out, int out_size, void* d_ws, size_t ws_size,
                              hipStream_t stream) {
    const float* x      = (const float*)d_in[0];
    const float* W      = (const float*)d_in[1];
    const float* a      = (const float*)d_in[2];
    const int*   adj    = (const int*)d_in[3];
    const float* adj_we = (const float*)d_in[4];
    float* out = (float*)d_out;

    float*  Wt   = (float*)d_ws;                       // 8192 fp32
    ushort* ht   = (ushort*)(Wt + 8192);               // 128*64*512 bf16
    float*  srcv = (float*)(ht + BTOT * FOUT * NN);    // 65536 fp32
    float*  dstv = srcv + BTOT * NN;                   // 65536 fp32

    hipLaunchKernelGGL(k_transpose_w, dim3(32), dim3(256), 0, stream, W, Wt);
    hipLaunchKernelGGL(k_feat, dim3(8, 128), dim3(256), 0, stream,
                       x, Wt, a, ht, srcv, dstv);
    hipLaunchKernelGGL(k_attn, dim3(8, 128), dim3(256), 0, stream,
                       ht, srcv, dstv, adj, adj_we, out);
}

// Round 3
// 62.152 us; speedup vs baseline: 1.9668x; 1.1442x over previous
//
#include <hip/hip_runtime.h>
#include <hip/hip_bf16.h>

#define BTOT 128     // B*T
#define NN   512
#define FIN  128
#define FOUT 64
#define NEG_INF -9000000000000000.0f

typedef __attribute__((ext_vector_type(8))) short bf16x8;
typedef __attribute__((ext_vector_type(4))) float f32x4;

static __device__ inline ushort f2bf(float f) {
    __hip_bfloat16 h = __float2bfloat16(f);
    return *(ushort*)&h;
}
static __device__ inline float bf2f(ushort u) {
    uint v = (uint)u << 16;
    return __uint_as_float(v);
}

// ---------- P: split W[o][k] fp32 -> Whi/Wlo bf16 (same [o][k] layout) ----------
__global__ void k_prep_w(const float* __restrict__ W,
                         ushort* __restrict__ Whi, ushort* __restrict__ Wlo) {
    int i = blockIdx.x * 256 + threadIdx.x;      // 8192 total
    float w = W[i];
    ushort hi = f2bf(w);
    Whi[i] = hi;
    Wlo[i] = f2bf(w - bf2f(hi));
}

// ---------- A: h = x @ W^T via bf16x3 MFMA; emit ht bf16 [bt][o][n], src, dst ----
// grid (8, 128), 256 threads = 4 waves; wave wv owns rows n0+wv*16 .. +15.
// No LDS, no barriers.
__global__ void k_feat(const float* __restrict__ x, const ushort* __restrict__ Whi,
                       const ushort* __restrict__ Wlo, const float* __restrict__ a,
                       ushort* __restrict__ ht, float* __restrict__ srcv,
                       float* __restrict__ dstv) {
    const int t    = threadIdx.x;
    const int bt   = blockIdx.y;
    const int wv   = t >> 6, lane = t & 63;
    const int r    = lane & 15;          // A-row / B-col within 16; C/D col
    const int kc   = lane >> 4;          // k-chunk; C/D row group
    const int n0   = blockIdx.x * 64 + wv * 16;

    const float* xrow = x + ((long)bt * NN + n0 + r) * FIN;

    f32x4 acc[4] = {{0,0,0,0},{0,0,0,0},{0,0,0,0},{0,0,0,0}};

#pragma unroll
    for (int ks = 0; ks < 4; ++ks) {
        float4 xa = *(const float4*)&xrow[ks * 32 + kc * 8];
        float4 xb = *(const float4*)&xrow[ks * 32 + kc * 8 + 4];
        float xv[8] = {xa.x, xa.y, xa.z, xa.w, xb.x, xb.y, xb.z, xb.w};
        bf16x8 Ahi, Alo;
#pragma unroll
        for (int e = 0; e < 8; ++e) {
            ushort h = f2bf(xv[e]);
            Ahi[e] = (short)h;
            Alo[e] = (short)f2bf(xv[e] - bf2f(h));
        }
#pragma unroll
        for (int g = 0; g < 4; ++g) {
            const int wo = (g * 16 + r) * FIN + ks * 32 + kc * 8;
            bf16x8 Bhi = *(const bf16x8*)&Whi[wo];
            bf16x8 Blo = *(const bf16x8*)&Wlo[wo];
            acc[g] = __builtin_amdgcn_mfma_f32_16x16x32_bf16(Ahi, Bhi, acc[g], 0, 0, 0);
            acc[g] = __builtin_amdgcn_mfma_f32_16x16x32_bf16(Alo, Bhi, acc[g], 0, 0, 0);
            acc[g] = __builtin_amdgcn_mfma_f32_16x16x32_bf16(Ahi, Blo, acc[g], 0, 0, 0);
        }
    }

    // C/D layout: col = lane&15 (o within g*16), row = kc*4 + reg (n within 16)
    // src/dst: s[n] = sum_o h[n][o] * a{1,2}[o]
    float a1g[4], a2g[4];
#pragma unroll
    for (int g = 0; g < 4; ++g) {
        a1g[g] = a[g * 16 + r];
        a2g[g] = a[FOUT + g * 16 + r];
    }
    f32x4 s1v = {0,0,0,0}, s2v = {0,0,0,0};
#pragma unroll
    for (int g = 0; g < 4; ++g)
#pragma unroll
        for (int reg = 0; reg < 4; ++reg) {
            s1v[reg] += acc[g][reg] * a1g[g];
            s2v[reg] += acc[g][reg] * a2g[g];
        }
#pragma unroll
    for (int off = 8; off; off >>= 1)
#pragma unroll
        for (int reg = 0; reg < 4; ++reg) {
            s1v[reg] += __shfl_down(s1v[reg], off, 16);
            s2v[reg] += __shfl_down(s2v[reg], off, 16);
        }
    if (r == 0) {
        float4 o1 = make_float4(s1v[0], s1v[1], s1v[2], s1v[3]);
        float4 o2 = make_float4(s2v[0], s2v[1], s2v[2], s2v[3]);
        *(float4*)&srcv[bt * NN + n0 + kc * 4] = o1;
        *(float4*)&dstv[bt * NN + n0 + kc * 4] = o2;
    }

    // ht[bt][o][n] bf16: lane holds 4 consecutive n (regs) for o = g*16+r
#pragma unroll
    for (int g = 0; g < 4; ++g) {
        uint2 pk;
        pk.x = (uint)f2bf(acc[g][0]) | ((uint)f2bf(acc[g][1]) << 16);
        pk.y = (uint)f2bf(acc[g][2]) | ((uint)f2bf(acc[g][3]) << 16);
        *(uint2*)&ht[(long)bt * (FOUT * NN) + (g * 16 + r) * NN + n0 + kc * 4] = pk;
    }
}

// ---------- B: fused att (exp, no-max softmax) + bf16 MFMA PV ----------
// grid (8, 128), 256 threads = 4 waves. Block: 64 i-rows x 64 o-cols, 8 j-tiles.
__global__ void k_attn(const ushort* __restrict__ ht, const float* __restrict__ srcv,
                       const float* __restrict__ dstv, const int* __restrict__ adj,
                       const float* __restrict__ adj_we, float* __restrict__ out) {
    __shared__ ushort ps[64 * 72];   // p tile bf16 [i][k], stride 72
    __shared__ ushort hs[64 * 72];   // h^T tile bf16 [o][k], stride 72
    __shared__ float dst_s[NN];
    __shared__ float src_s[64];

    const int t    = threadIdx.x;
    const int bt   = blockIdx.y;
    const int i0   = blockIdx.x * 64;
    const int lane = t & 63;
    const int wv   = t >> 6;

    if (t < 64) src_s[t] = srcv[bt * NN + i0 + t];
    for (int r = t; r < NN; r += 256) dst_s[r] = dstv[bt * NN + r];

    const int pi = t >> 2;           // p-compute: row
    const int pj = (t & 3) * 16;     // p-compute: col base (16 consecutive j)
    const int* adjr  = adj + (i0 + pi) * NN;
    const float* wr  = adj_we + (i0 + pi) * NN;
    const ushort* htb = ht + bt * (FOUT * NN);

    f32x4 acc0 = {0,0,0,0}, acc1 = {0,0,0,0}, acc2 = {0,0,0,0},
          acc3 = {0,0,0,0}, accd = {0,0,0,0};

    bf16x8 ones;
#pragma unroll
    for (int j = 0; j < 8; ++j) ones[j] = (short)0x3F80;   // bf16 1.0

    __syncthreads();
    const float si = src_s[pi];

    const int arow = (wv * 16 + (lane & 15)) * 72;   // A-frag row base
    const int koff = (lane >> 4) * 8;                // k-chunk within frag

    for (int jt = 0; jt < 8; ++jt) {
        const int j0 = jt * 64;

        // stage hs (bf16, contiguous 16B per lane)
#pragma unroll
        for (int q = 0; q < 2; ++q) {
            int idx = 2 * t + q;             // 0..511
            int row = idx >> 3, c8 = idx & 7;
            float4 v = *(const float4*)&htb[row * NN + j0 + c8 * 8];
            *(float4*)&hs[row * 72 + c8 * 8] = v;
        }

        // compute p (16 elems per thread, contiguous j), pack bf16
        ushort pu[16];
#pragma unroll
        for (int q = 0; q < 4; ++q) {
            int4   av4 = *(const int4*)&adjr[j0 + pj + 4 * q];
            float4 wv4 = *(const float4*)&wr[j0 + pj + 4 * q];
            float4 dv4 = *(const float4*)&dst_s[j0 + pj + 4 * q];
#pragma unroll
            for (int e = 0; e < 4; ++e) {
                int   ad = ((const int*)&av4)[e];
                float w  = ((const float*)&wv4)[e];
                float s  = si + ((const float*)&dv4)[e];
                float lr = s > 0.f ? s : 0.01f * s;
                float att = (ad > 0 ? lr : NEG_INF) * w;   // matches ref incl. w==0
                pu[4 * q + e] = f2bf(__expf(att));          // masked -> 0
            }
        }
        *(float4*)&ps[pi * 72 + pj]     = *(float4*)&pu[0];
        *(float4*)&ps[pi * 72 + pj + 8] = *(float4*)&pu[8];
        __syncthreads();

        // MFMA: wave wv owns rows 16wv..16wv+15, all 64 o-cols + den
#pragma unroll
        for (int s = 0; s < 2; ++s) {
            bf16x8 afr = *(bf16x8*)&ps[arow + s * 32 + koff];
            bf16x8 b0  = *(bf16x8*)&hs[( 0 + (lane & 15)) * 72 + s * 32 + koff];
            bf16x8 b1  = *(bf16x8*)&hs[(16 + (lane & 15)) * 72 + s * 32 + koff];
            bf16x8 b2  = *(bf16x8*)&hs[(32 + (lane & 15)) * 72 + s * 32 + koff];
            bf16x8 b3  = *(bf16x8*)&hs[(48 + (lane & 15)) * 72 + s * 32 + koff];
            acc0 = __builtin_amdgcn_mfma_f32_16x16x32_bf16(afr, b0, acc0, 0, 0, 0);
            acc1 = __builtin_amdgcn_mfma_f32_16x16x32_bf16(afr, b1, acc1, 0, 0, 0);
            acc2 = __builtin_amdgcn_mfma_f32_16x16x32_bf16(afr, b2, acc2, 0, 0, 0);
            acc3 = __builtin_amdgcn_mfma_f32_16x16x32_bf16(afr, b3, acc3, 0, 0, 0);
            accd = __builtin_amdgcn_mfma_f32_16x16x32_bf16(afr, ones, accd, 0, 0, 0);
        }
        __syncthreads();
    }

    // epilogue: C/D layout col=lane&15, row=(lane>>4)*4+reg; den in accd same slots
    const int orow = wv * 16 + (lane >> 4) * 4;
    const int ocol = lane & 15;
    float* ob = out + ((long)bt * NN + i0) * FOUT;
#pragma unroll
    for (int reg = 0; reg < 4; ++reg) {
        float inv = 1.0f / accd[reg];
        ob[(orow + reg) * FOUT +  0 + ocol] = acc0[reg] * inv;
        ob[(orow + reg) * FOUT + 16 + ocol] = acc1[reg] * inv;
        ob[(orow + reg) * FOUT + 32 + ocol] = acc2[reg] * inv;
        ob[(orow + reg) * FOUT + 48 + ocol] = acc3[reg] * inv;
    }
}

extern "C" void kernel_launch(void* const* d_in, const int* in_sizes, int n_in,
                              void* d_out, int out_size, void* d_ws, size_t ws_size,
                              hipStream_t stream) {
    const float* x      = (const float*)d_in[0];
    const float* W      = (const float*)d_in[1];
    const float* a      = (const float*)d_in[2];
    const int*   adj    = (const int*)d_in[3];
    const float* adj_we = (const float*)d_in[4];
    float* out = (float*)d_out;

    ushort* Whi  = (ushort*)d_ws;                      // 8192 bf16
    ushort* Wlo  = Whi + FOUT * FIN;                   // 8192 bf16
    ushort* ht   = Wlo + FOUT * FIN;                   // 128*64*512 bf16
    float*  srcv = (float*)(ht + BTOT * FOUT * NN);    // 65536 fp32
    float*  dstv = srcv + BTOT * NN;                   // 65536 fp32

    hipLaunchKernelGGL(k_prep_w, dim3(32), dim3(256), 0, stream, W, Whi, Wlo);
    hipLaunchKernelGGL(k_feat, dim3(8, 128), dim3(256), 0, stream,
                       x, Whi, Wlo, a, ht, srcv, dstv);
    hipLaunchKernelGGL(k_attn, dim3(8, 128), dim3(256), 0, stream,
                       ht, srcv, dstv, adj, adj_we, out);
}

// Round 4
// 55.647 us; speedup vs baseline: 2.1967x; 1.1169x over previous
//
#include <hip/hip_runtime.h>
#include <hip/hip_bf16.h>

#define BTOT 128     // B*T
#define NN   512
#define FIN  128
#define FOUT 64
#define NEG_INF -9000000000000000.0f

typedef __attribute__((ext_vector_type(8))) short bf16x8;
typedef __attribute__((ext_vector_type(4))) float f32x4;

static __device__ inline ushort f2bf(float f) {
    __hip_bfloat16 h = __float2bfloat16(f);
    return *(ushort*)&h;
}
static __device__ inline float bf2f(ushort u) {
    uint v = (uint)u << 16;
    return __uint_as_float(v);
}

// ---------- P0: split W[o][k] fp32 -> Whi/Wlo bf16 (same [o][k] layout) ----------
__global__ void k_prep_w(const float* __restrict__ W,
                         ushort* __restrict__ Whi, ushort* __restrict__ Wlo) {
    int i = blockIdx.x * 256 + threadIdx.x;      // 8192 total
    float w = W[i];
    ushort hi = f2bf(w);
    Whi[i] = hi;
    Wlo[i] = f2bf(w - bf2f(hi));
}

// ---------- P1: pack adj + adj_we -> wsg: conn ? w : -w-1 (exact) ----------
__global__ void k_prep_adj(const int* __restrict__ adj, const float* __restrict__ we,
                           float* __restrict__ wsg) {
    int i = (blockIdx.x * 256 + threadIdx.x) * 4;   // 262144 total
    int4   a4 = *(const int4*)&adj[i];
    float4 w4 = *(const float4*)&we[i];
    float4 o;
    o.x = a4.x > 0 ? w4.x : -w4.x - 1.0f;
    o.y = a4.y > 0 ? w4.y : -w4.y - 1.0f;
    o.z = a4.z > 0 ? w4.z : -w4.z - 1.0f;
    o.w = a4.w > 0 ? w4.w : -w4.w - 1.0f;
    *(float4*)&wsg[i] = o;
}

// ---------- A: h = x @ W^T via bf16x3 MFMA; emit ht bf16 [bt][o][n], src, dst ----
// grid (8, 128), 256 threads = 4 waves; wave wv owns rows n0+wv*16 .. +15.
// No LDS, no barriers.
__global__ void k_feat(const float* __restrict__ x, const ushort* __restrict__ Whi,
                       const ushort* __restrict__ Wlo, const float* __restrict__ a,
                       ushort* __restrict__ ht, float* __restrict__ srcv,
                       float* __restrict__ dstv) {
    const int t    = threadIdx.x;
    const int bt   = blockIdx.y;
    const int wv   = t >> 6, lane = t & 63;
    const int r    = lane & 15;          // A-row / B-col within 16; C/D col
    const int kc   = lane >> 4;          // k-chunk; C/D row group
    const int n0   = blockIdx.x * 64 + wv * 16;

    const float* xrow = x + ((long)bt * NN + n0 + r) * FIN;

    f32x4 acc[4] = {{0,0,0,0},{0,0,0,0},{0,0,0,0},{0,0,0,0}};

#pragma unroll
    for (int ks = 0; ks < 4; ++ks) {
        float4 xa = *(const float4*)&xrow[ks * 32 + kc * 8];
        float4 xb = *(const float4*)&xrow[ks * 32 + kc * 8 + 4];
        float xv[8] = {xa.x, xa.y, xa.z, xa.w, xb.x, xb.y, xb.z, xb.w};
        bf16x8 Ahi, Alo;
#pragma unroll
        for (int e = 0; e < 8; ++e) {
            ushort h = f2bf(xv[e]);
            Ahi[e] = (short)h;
            Alo[e] = (short)f2bf(xv[e] - bf2f(h));
        }
#pragma unroll
        for (int g = 0; g < 4; ++g) {
            const int wo = (g * 16 + r) * FIN + ks * 32 + kc * 8;
            bf16x8 Bhi = *(const bf16x8*)&Whi[wo];
            bf16x8 Blo = *(const bf16x8*)&Wlo[wo];
            acc[g] = __builtin_amdgcn_mfma_f32_16x16x32_bf16(Ahi, Bhi, acc[g], 0, 0, 0);
            acc[g] = __builtin_amdgcn_mfma_f32_16x16x32_bf16(Alo, Bhi, acc[g], 0, 0, 0);
            acc[g] = __builtin_amdgcn_mfma_f32_16x16x32_bf16(Ahi, Blo, acc[g], 0, 0, 0);
        }
    }

    // C/D layout: col = lane&15 (o within g*16), row = kc*4 + reg (n within 16)
    // src/dst: s[n] = sum_o h[n][o] * a{1,2}[o]
    float a1g[4], a2g[4];
#pragma unroll
    for (int g = 0; g < 4; ++g) {
        a1g[g] = a[g * 16 + r];
        a2g[g] = a[FOUT + g * 16 + r];
    }
    f32x4 s1v = {0,0,0,0}, s2v = {0,0,0,0};
#pragma unroll
    for (int g = 0; g < 4; ++g)
#pragma unroll
        for (int reg = 0; reg < 4; ++reg) {
            s1v[reg] += acc[g][reg] * a1g[g];
            s2v[reg] += acc[g][reg] * a2g[g];
        }
#pragma unroll
    for (int off = 8; off; off >>= 1)
#pragma unroll
        for (int reg = 0; reg < 4; ++reg) {
            s1v[reg] += __shfl_down(s1v[reg], off, 16);
            s2v[reg] += __shfl_down(s2v[reg], off, 16);
        }
    if (r == 0) {
        float4 o1 = make_float4(s1v[0], s1v[1], s1v[2], s1v[3]);
        float4 o2 = make_float4(s2v[0], s2v[1], s2v[2], s2v[3]);
        *(float4*)&srcv[bt * NN + n0 + kc * 4] = o1;
        *(float4*)&dstv[bt * NN + n0 + kc * 4] = o2;
    }

    // ht[bt][o][n] bf16: lane holds 4 consecutive n (regs) for o = g*16+r
#pragma unroll
    for (int g = 0; g < 4; ++g) {
        uint2 pk;
        pk.x = (uint)f2bf(acc[g][0]) | ((uint)f2bf(acc[g][1]) << 16);
        pk.y = (uint)f2bf(acc[g][2]) | ((uint)f2bf(acc[g][3]) << 16);
        *(uint2*)&ht[(long)bt * (FOUT * NN) + (g * 16 + r) * NN + n0 + kc * 4] = pk;
    }
}

// ---------- B: fused att (exp, no-max softmax) + bf16 MFMA PV ----------
// 1D grid 1024: blockIdx.x = bt*8 + i_tile  =>  XCD = i_tile (round-robin %8).
// All 128 bt-blocks of an i-tile share one XCD: its 256KB wsg slice stays L2-hot.
__global__ void k_attn(const ushort* __restrict__ ht, const float* __restrict__ srcv,
                       const float* __restrict__ dstv, const float* __restrict__ wsg,
                       float* __restrict__ out) {
    __shared__ ushort ps[64 * 72];   // p tile bf16 [i][k], stride 72
    __shared__ ushort hs[64 * 72];   // h^T tile bf16 [o][k], stride 72
    __shared__ float dst_s[NN];
    __shared__ float src_s[64];

    const int t    = threadIdx.x;
    const int bid  = blockIdx.x;
    const int bt   = bid >> 3;
    const int i0   = (bid & 7) << 6;
    const int lane = t & 63;
    const int wv   = t >> 6;

    if (t < 64) src_s[t] = srcv[bt * NN + i0 + t];
    for (int r = t; r < NN; r += 256) dst_s[r] = dstv[bt * NN + r];

    const int pi = t >> 2;           // p-compute: row
    const int pj = (t & 3) * 16;     // p-compute: col base (16 consecutive j)
    const float* wr   = wsg + (i0 + pi) * NN;
    const ushort* htb = ht + bt * (FOUT * NN);

    f32x4 acc0 = {0,0,0,0}, acc1 = {0,0,0,0}, acc2 = {0,0,0,0},
          acc3 = {0,0,0,0}, accd = {0,0,0,0};

    bf16x8 ones;
#pragma unroll
    for (int j = 0; j < 8; ++j) ones[j] = (short)0x3F80;   // bf16 1.0

    __syncthreads();
    const float si = src_s[pi];

    const int arow = (wv * 16 + (lane & 15)) * 72;   // A-frag row base
    const int koff = (lane >> 4) * 8;                // k-chunk within frag

    for (int jt = 0; jt < 8; ++jt) {
        const int j0 = jt * 64;

        // stage hs (bf16, contiguous 16B per lane)
#pragma unroll
        for (int q = 0; q < 2; ++q) {
            int idx = 2 * t + q;             // 0..511
            int row = idx >> 3, c8 = idx & 7;
            float4 v = *(const float4*)&htb[row * NN + j0 + c8 * 8];
            *(float4*)&hs[row * 72 + c8 * 8] = v;
        }

        // compute p (16 elems per thread, contiguous j), pack bf16
        ushort pu[16];
#pragma unroll
        for (int q = 0; q < 4; ++q) {
            float4 vv4 = *(const float4*)&wr[j0 + pj + 4 * q];
            float4 dv4 = *(const float4*)&dst_s[j0 + pj + 4 * q];
#pragma unroll
            for (int e = 0; e < 4; ++e) {
                float v  = ((const float*)&vv4)[e];
                bool  cn = v >= -0.5f;                    // conn?
                float w  = cn ? v : -(v + 1.0f);          // exact decode
                float s  = si + ((const float*)&dv4)[e];
                float lr = fmaxf(s, 0.01f * s);           // leaky_relu
                float att = (cn ? lr : NEG_INF) * w;      // matches ref incl. w==0
                pu[4 * q + e] = f2bf(__expf(att));        // masked -> 0
            }
        }
        *(float4*)&ps[pi * 72 + pj]     = *(float4*)&pu[0];
        *(float4*)&ps[pi * 72 + pj + 8] = *(float4*)&pu[8];
        __syncthreads();

        // MFMA: wave wv owns rows 16wv..16wv+15, all 64 o-cols + den
#pragma unroll
        for (int s = 0; s < 2; ++s) {
            bf16x8 afr = *(bf16x8*)&ps[arow + s * 32 + koff];
            bf16x8 b0  = *(bf16x8*)&hs[( 0 + (lane & 15)) * 72 + s * 32 + koff];
            bf16x8 b1  = *(bf16x8*)&hs[(16 + (lane & 15)) * 72 + s * 32 + koff];
            bf16x8 b2  = *(bf16x8*)&hs[(32 + (lane & 15)) * 72 + s * 32 + koff];
            bf16x8 b3  = *(bf16x8*)&hs[(48 + (lane & 15)) * 72 + s * 32 + koff];
            acc0 = __builtin_amdgcn_mfma_f32_16x16x32_bf16(afr, b0, acc0, 0, 0, 0);
            acc1 = __builtin_amdgcn_mfma_f32_16x16x32_bf16(afr, b1, acc1, 0, 0, 0);
            acc2 = __builtin_amdgcn_mfma_f32_16x16x32_bf16(afr, b2, acc2, 0, 0, 0);
            acc3 = __builtin_amdgcn_mfma_f32_16x16x32_bf16(afr, b3, acc3, 0, 0, 0);
            accd = __builtin_amdgcn_mfma_f32_16x16x32_bf16(afr, ones, accd, 0, 0, 0);
        }
        __syncthreads();
    }

    // epilogue: C/D layout col=lane&15, row=(lane>>4)*4+reg; den in accd same slots
    const int orow = wv * 16 + (lane >> 4) * 4;
    const int ocol = lane & 15;
    float* ob = out + ((long)bt * NN + i0) * FOUT;
#pragma unroll
    for (int reg = 0; reg < 4; ++reg) {
        float inv = 1.0f / accd[reg];
        ob[(orow + reg) * FOUT +  0 + ocol] = acc0[reg] * inv;
        ob[(orow + reg) * FOUT + 16 + ocol] = acc1[reg] * inv;
        ob[(orow + reg) * FOUT + 32 + ocol] = acc2[reg] * inv;
        ob[(orow + reg) * FOUT + 48 + ocol] = acc3[reg] * inv;
    }
}

extern "C" void kernel_launch(void* const* d_in, const int* in_sizes, int n_in,
                              void* d_out, int out_size, void* d_ws, size_t ws_size,
                              hipStream_t stream) {
    const float* x      = (const float*)d_in[0];
    const float* W      = (const float*)d_in[1];
    const float* a      = (const float*)d_in[2];
    const int*   adj    = (const int*)d_in[3];
    const float* adj_we = (const float*)d_in[4];
    float* out = (float*)d_out;

    ushort* Whi  = (ushort*)d_ws;                      // 8192 bf16
    ushort* Wlo  = Whi + FOUT * FIN;                   // 8192 bf16
    ushort* ht   = Wlo + FOUT * FIN;                   // 128*64*512 bf16
    float*  srcv = (float*)(ht + BTOT * FOUT * NN);    // 65536 fp32
    float*  dstv = srcv + BTOT * NN;                   // 65536 fp32
    float*  wsg  = dstv + BTOT * NN;                   // 262144 fp32

    hipLaunchKernelGGL(k_prep_w, dim3(32), dim3(256), 0, stream, W, Whi, Wlo);
    hipLaunchKernelGGL(k_prep_adj, dim3(256), dim3(256), 0, stream, adj, adj_we, wsg);
    hipLaunchKernelGGL(k_feat, dim3(8, 128), dim3(256), 0, stream,
                       x, Whi, Wlo, a, ht, srcv, dstv);
    hipLaunchKernelGGL(k_attn, dim3(1024), dim3(256), 0, stream,
                       ht, srcv, dstv, wsg, out);
}